// Round 6
// baseline (103.790 us; speedup 1.0000x reference)
//
#include <hip/hip_runtime.h>
#include <hip/hip_bf16.h>

typedef __attribute__((ext_vector_type(4))) int i32x4;
typedef __attribute__((ext_vector_type(4))) float f32x4;

#define BM 128
#define BN 128
#define THREADS 256
#define ABUF 8192          // A tile: 128 rows x 64 B
#define SA_OFF 32768       // after 4-slot A ring
#define SB_OFF 34816
#define LDS_TOTAL 36864

#define VMCNT(n) asm volatile("s_waitcnt vmcnt(" #n ")" ::: "memory")
#define MFMAI8(a, b, c) __builtin_amdgcn_mfma_i32_16x16x64_i8((a), (b), (c), 0, 0, 0)

static __device__ inline void gload_lds16(const void* g, void* l) {
  __builtin_amdgcn_global_load_lds((__attribute__((address_space(1))) void*)g,
                                   (__attribute__((address_space(3))) void*)l,
                                   16, 0, 0);
}

// ---------------- QDQ -> i8 (2q in {0,+-1,+-2}) + f32 group scales -------------------
// x -> qx row-major [M,K]; w -> Bc K-chunked [K/64][N][64] for coalesced B-frag loads.
__global__ __launch_bounds__(256) void qdq_i8(const float* __restrict__ x,
                                              signed char* __restrict__ qx,
                                              float* __restrict__ sax, int gx,
                                              const float* __restrict__ w,
                                              signed char* __restrict__ bc,
                                              float* __restrict__ sbx, int N, int gtot) {
  int g = (blockIdx.x << 2) + (threadIdx.x >> 6);
  if (g >= gtot) return;
  const int lane = threadIdx.x & 63;
  const bool isx = (g < gx);
  const int gl = isx ? g : g - gx;
  const float* src = isx ? x : w;

  const size_t base = (size_t)gl * 256 + (size_t)lane * 4;
  float4 v = *reinterpret_cast<const float4*>(src + base);
  float amax = fmaxf(fmaxf(fabsf(v.x), fabsf(v.y)), fmaxf(fabsf(v.z), fabsf(v.w)));
#pragma unroll
  for (int off = 32; off > 0; off >>= 1)
    amax = fmaxf(amax, __shfl_xor(amax, off, 64));
  const float scale = fmaxf(amax, 1e-6f);
  float in[4] = {v.x, v.y, v.z, v.w};
  int packed = 0;
#pragma unroll
  for (int i = 0; i < 4; ++i) {
    float t = fabsf(in[i] / scale);                // same op order as reference
    int q2 = t < 0.25f ? 0 : (t < 0.75f ? 1 : 2);  // = 2*q, exact
    if (in[i] < 0.0f) q2 = -q2;
    packed |= (q2 & 0xff) << (i * 8);
  }
  if (isx) {
    ((int*)qx)[(size_t)gl * 64 + lane] = packed;
    if (lane == 0) sax[gl] = scale;
  } else {
    const int n = gl >> 2, gk = gl & 3;            // row n, K-group gk (K=1024)
    const int t = gk * 4 + (lane >> 4);            // K-tile index
    ((int*)bc)[((size_t)t * N + n) * 16 + (lane & 15)] = packed;
    if (lane == 0) sbx[gl] = scale;
  }
}

// ---------------- GEMM i8: A via LDS ring, B direct-from-L2 (chunked layout) ---------
// 4 waves (2x2 of 64x64). A ring: 4 x 8KB, pair-line swizzle (r3/r5-verified, 0 confl).
// Per iter: prefetch B(t+1) regs -> VMCNT(counted) -> barrier -> STAGE A(t+3) ->
// ds_read A-frags -> 16 MFMA -> fold every 4th tile (exact i32 segment partials).
__global__ __launch_bounds__(THREADS, 2) void gemm_i8(
    const signed char* __restrict__ A8,  // [M,K]
    const signed char* __restrict__ Bc,  // [K/64][N][64]
    const float* __restrict__ sax,       // [M*4]
    const float* __restrict__ sbx,       // [N*4]
    const float* __restrict__ bias,      // [N]
    float* __restrict__ C,               // [M,N]
    int M, int N, int K) {
  extern __shared__ char smem[];

  const int tid = threadIdx.x;
  const int lane = tid & 63;
  const int wid = tid >> 6;
  const int wm = wid >> 1, wn = wid & 1;
  const int fr = lane & 15, hi = lane >> 4;

  const int nwg = gridDim.x;
  int bid = blockIdx.x;
  if ((nwg & 7) == 0) bid = (bid & 7) * (nwg >> 3) + (bid >> 3);
  const int ntn = N / BN;
  const int tm = bid / ntn, tn = bid % ntn;
  const int m0 = tm * BM, n0 = tn * BN;

  float* sa_lds = (float*)(smem + SA_OFF);
  float* sb_lds = (float*)(smem + SB_OFF);
#pragma unroll
  for (int p = 0; p < 2; ++p) {
    int idx = p * 256 + tid, row = idx & 127, gg = idx >> 7;
    sa_lds[gg * 128 + row] = sax[(size_t)(m0 + row) * 4 + gg];
    sb_lds[gg * 128 + row] = sbx[(size_t)(n0 + row) * 4 + gg];
  }

  // A staging source (inverse pair-line swizzle; verified 0-conflict r3/r5)
  const int u = (tid & 7) ^ ((tid >> 3) & 7);
  const int r0s = 2 * (tid >> 3) + (u >> 2);
  const int cBs = (u & 3) * 16;
  const size_t srcA = (size_t)(m0 + r0s) * K + cBs;
  const size_t rowStep = (size_t)64 * K;
  const int d16 = tid * 16;

#define STAGE_A(bufi, tt) do {                                  \
    char* bb = smem + (bufi) * ABUF;                            \
    const signed char* ga = A8 + srcA + (size_t)(tt) * 64;      \
    gload_lds16(ga, bb + d16);                                  \
    gload_lds16(ga + rowStep, bb + 4096 + d16);                 \
  } while (0)

  // swizzled A-frag read base: row = wm*64 + i*16 + fr, chunk hi
  const int slot16 = ((hi + 4 * (fr & 1)) ^ (fr >> 1)) << 4;
  const int aBase = (wm * 32 + (fr >> 1)) * 128 + slot16;  // + i*1024

  // B direct: frag j at Bw + t*N*64 + j*1024 (fully coalesced 1024B per frag)
  const size_t NB64 = (size_t)N * 64;
  const signed char* Bw = Bc + (size_t)(n0 + wn * 64) * 64 + (size_t)fr * 64 + hi * 16;

  f32x4 master[4][4];
  i32x4 acc[4][4];
#pragma unroll
  for (int i = 0; i < 4; ++i)
#pragma unroll
    for (int j = 0; j < 4; ++j) {
      master[i][j] = (f32x4){0.f, 0.f, 0.f, 0.f};
      acc[i][j] = (i32x4){0, 0, 0, 0};
    }

#define FOLD(tc) do {                                                          \
    const int gI = (tc) >> 2;                                                  \
    f32x4 sav[4]; float sbq[4];                                                \
    _Pragma("unroll") for (int i = 0; i < 4; ++i)                              \
      sav[i] = *(const f32x4*)(sa_lds + gI * 128 + wm * 64 + i * 16 + hi * 4); \
    _Pragma("unroll") for (int j = 0; j < 4; ++j)                              \
      sbq[j] = sb_lds[gI * 128 + wn * 64 + j * 16 + fr] * 0.25f;               \
    _Pragma("unroll") for (int i = 0; i < 4; ++i)                              \
      _Pragma("unroll") for (int j = 0; j < 4; ++j) {                          \
        f32x4 s = sav[i] * sbq[j];                                             \
        _Pragma("unroll") for (int r = 0; r < 4; ++r)                          \
          master[i][j][r] += (float)acc[i][j][r] * s[r];                       \
        acc[i][j] = (i32x4){0, 0, 0, 0};                                       \
      }                                                                        \
  } while (0)

#define COMPUTE_SUB(tc, bREG) do {                                             \
    const char* ab = smem + ((tc) & 3) * ABUF;                                 \
    i32x4 a[4];                                                                \
    _Pragma("unroll") for (int i = 0; i < 4; ++i)                              \
      a[i] = *(const i32x4*)(ab + aBase + i * 1024);                           \
    __builtin_amdgcn_s_setprio(1);                                             \
    _Pragma("unroll") for (int i = 0; i < 4; ++i)                              \
      _Pragma("unroll") for (int j = 0; j < 4; ++j)                            \
        acc[i][j] = MFMAI8(a[i], bREG[j], acc[i][j]);                          \
    __builtin_amdgcn_s_setprio(0);                                             \
    if (((tc) & 3) == 3) FOLD(tc);                                             \
  } while (0)

  const int T = K / 64;  // 16
  __syncthreads();       // scales visible before any fold
  STAGE_A(0, 0);
  STAGE_A(1, 1);
  STAGE_A(2, 2);

  i32x4 b0[4], b1[4];
#pragma unroll
  for (int j = 0; j < 4; ++j) b0[j] = *(const i32x4*)(Bw + j * 1024);

  for (int t = 0; t < T; t += 2) {
    // ---- even sub-iter (tc = t): uses b0, prefetch b1(t+1) ----
    if (t + 1 < T) {
#pragma unroll
      for (int j = 0; j < 4; ++j)
        b1[j] = *(const i32x4*)(Bw + (size_t)(t + 1) * NB64 + j * 1024);
    }
    // counted gate for A(t): issues newer than A(t) in steady state = 16
    if (t == 0) { VMCNT(12); } else if (t < T - 2) { VMCNT(16); } else { VMCNT(14); }
    __builtin_amdgcn_s_barrier();
    if (t + 3 < T) STAGE_A((t + 3) & 3, t + 3);
    COMPUTE_SUB(t, b0);

    // ---- odd sub-iter (tc = t+1): uses b1, prefetch b0(t+2) ----
    if (t + 2 < T) {
#pragma unroll
      for (int j = 0; j < 4; ++j)
        b0[j] = *(const i32x4*)(Bw + (size_t)(t + 2) * NB64 + j * 1024);
    }
    if (t + 1 < T - 1) { VMCNT(16); } else { VMCNT(8); }
    __builtin_amdgcn_s_barrier();
    if (t + 4 < T) STAGE_A((t + 4) & 3, t + 4);
    COMPUTE_SUB(t + 1, b1);
  }
#undef COMPUTE_SUB
#undef FOLD
#undef STAGE_A

  // epilogue: C[row][col] = master + bias[col]
#pragma unroll
  for (int j = 0; j < 4; ++j) {
    const int col = n0 + wn * 64 + j * 16 + fr;
    const float bv = bias[col];
#pragma unroll
    for (int i = 0; i < 4; ++i) {
      const int row0 = m0 + wm * 64 + i * 16 + hi * 4;
#pragma unroll
      for (int r = 0; r < 4; ++r)
        C[(size_t)(row0 + r) * N + col] = master[i][j][r] + bv;
    }
  }
}

extern "C" void kernel_launch(void* const* d_in, const int* in_sizes, int n_in,
                              void* d_out, int out_size, void* d_ws, size_t ws_size,
                              hipStream_t stream) {
  const float* x = (const float*)d_in[0];     // [M,K]
  const float* w = (const float*)d_in[1];     // [N,K]
  const float* bias = (const float*)d_in[2];  // [N]
  float* out = (float*)d_out;

  const int MK = in_sizes[0];
  const int NK = in_sizes[1];
  const int N = in_sizes[2];
  const int K = NK / N;
  const int M = MK / K;

  signed char* qx8 = (signed char*)d_ws;           // [M,K] i8
  signed char* bc = qx8 + (size_t)MK;              // [K/64][N][64] i8
  float* sax = (float*)(bc + (size_t)NK);          // MK/256
  float* sbx = sax + (size_t)(MK / 256);           // NK/256

  const int gx = MK / 256;
  const int gtot = gx + NK / 256;
  qdq_i8<<<(gtot + 3) / 4, 256, 0, stream>>>(x, qx8, sax, gx, w, bc, sbx, N, gtot);

  hipFuncSetAttribute((const void*)gemm_i8, hipFuncAttributeMaxDynamicSharedMemorySize,
                      LDS_TOTAL);
  dim3 grid((M / BM) * (N / BN));
  gemm_i8<<<grid, dim3(THREADS), LDS_TOTAL, stream>>>(qx8, bc, sax, sbx, bias, out,
                                                      M, N, K);
}

// Round 7
// 98.992 us; speedup vs baseline: 1.0485x; 1.0485x over previous
//
#include <hip/hip_runtime.h>
#include <hip/hip_bf16.h>

typedef __attribute__((ext_vector_type(4))) int i32x4;
typedef __attribute__((ext_vector_type(4))) float f32x4;

#define BM 128
#define BN 128
#define THREADS 512
#define SLOT_BYTES 16384   // per K-tile slot: A 8KB + B 8KB
#define NSLOT 4
#define SA_OFF 65536       // f32 sa[4][128]
#define SB_OFF 67584       // f32 sb[4][128]
#define LDS_TOTAL 69632

#define VMCNT(n) asm volatile("s_waitcnt vmcnt(" #n ")" ::: "memory")
#define MFMAI8(a, b, c) __builtin_amdgcn_mfma_i32_16x16x64_i8((a), (b), (c), 0, 0, 0)

static __device__ inline void gload_lds16(const void* g, void* l) {
  __builtin_amdgcn_global_load_lds((__attribute__((address_space(1))) void*)g,
                                   (__attribute__((address_space(3))) void*)l,
                                   16, 0, 0);
}

// ---------------- QDQ -> i8 (2q in {0,+-1,+-2}) + f32 per-256-group scales ----------
// Exact vs reference: scale=max(absmax,1e-6); t=|x/scale|; q2 = 0 / 1 / 2.
__global__ __launch_bounds__(256) void qdq_i8(const float* __restrict__ x,
                                              signed char* __restrict__ qx,
                                              float* __restrict__ sax, int gx,
                                              const float* __restrict__ w,
                                              signed char* __restrict__ qw,
                                              float* __restrict__ sbx, int gtot) {
  int g = (blockIdx.x << 2) + (threadIdx.x >> 6);
  if (g >= gtot) return;
  const int lane = threadIdx.x & 63;
  const bool isx = (g < gx);
  const int gl = isx ? g : g - gx;
  const float* src = isx ? x : w;
  int* dst = (int*)(isx ? qx : qw);
  float* sc = isx ? sax : sbx;

  const size_t base = (size_t)gl * 256 + (size_t)lane * 4;
  float4 v = *reinterpret_cast<const float4*>(src + base);
  float amax = fmaxf(fmaxf(fabsf(v.x), fabsf(v.y)), fmaxf(fabsf(v.z), fabsf(v.w)));
#pragma unroll
  for (int off = 32; off > 0; off >>= 1)
    amax = fmaxf(amax, __shfl_xor(amax, off, 64));
  const float scale = fmaxf(amax, 1e-6f);
  float in[4] = {v.x, v.y, v.z, v.w};
  int packed = 0;
#pragma unroll
  for (int i = 0; i < 4; ++i) {
    float t = fabsf(in[i] / scale);
    int q2 = t < 0.25f ? 0 : (t < 0.75f ? 1 : 2);
    if (in[i] < 0.0f) q2 = -q2;
    packed |= (q2 & 0xff) << (i * 8);
  }
  dst[(size_t)gl * 64 + lane] = packed;
  if (lane == 0) sc[gl] = scale;
}

// ---------------- GEMM i8, 8 waves x (64x32), 4-slot ring, counted vmcnt -------------
// LDS slot: A[128r][64B] @0, B[128r][64B] @8192, pair-line swizzle (0-conflict, r3+):
//   byte(r,c16) = (r>>1)*128 + ((c + 4*(r&1)) ^ ((r>>1)&7))*16
// gload_lds dest linear; global SOURCE inverse-permuted; ds_read swizzled.
// Ring distance 3; STAGE(t+3) post-barrier overwrites slot of t-1 (reads done pre-bar).
// vmcnt gate at iter t = loads issued after STAGE(t): 4 steady, 2 at T-2, 0 at T-1.
__global__ __launch_bounds__(THREADS, 4) void gemm_i8(
    const signed char* __restrict__ A8,  // [M,K]
    const signed char* __restrict__ B8,  // [N,K]
    const float* __restrict__ sax,       // [M*4]
    const float* __restrict__ sbx,       // [N*4]
    const float* __restrict__ bias,      // [N]
    float* __restrict__ C,               // [M,N]
    int M, int N, int K) {
  extern __shared__ char smem[];

  const int tid = threadIdx.x;
  const int lane = tid & 63;
  const int wid = tid >> 6;     // 0..7
  const int wm = wid >> 2;      // 0..1 -> 64-row strip
  const int wn = wid & 3;       // 0..3 -> 32-col strip
  const int fr = lane & 15, hi = lane >> 4;

  const int nwg = gridDim.x;
  int bid = blockIdx.x;
  if ((nwg & 7) == 0) bid = (bid & 7) * (nwg >> 3) + (bid >> 3);
  const int ntn = N / BN;
  const int tm = bid / ntn, tn = bid % ntn;
  const int m0 = tm * BM, n0 = tn * BN;

  // scales: 512 threads cover 4 groups x 128 rows exactly
  float* sa_lds = (float*)(smem + SA_OFF);
  float* sb_lds = (float*)(smem + SB_OFF);
  {
    const int row = tid & 127, gg = tid >> 7;
    sa_lds[gg * 128 + row] = sax[(size_t)(m0 + row) * 4 + gg];
    sb_lds[gg * 128 + row] = sbx[(size_t)(n0 + row) * 4 + gg];
  }

  // staging source (inverse pair-line swizzle): dest D=tid*16 -> L=tid>>3, S=tid&7
  const int u = (tid & 7) ^ ((tid >> 3) & 7);
  const int r0s = 2 * (tid >> 3) + (u >> 2);   // 0..127
  const int cBs = (u & 3) * 16;
  const size_t srcA = (size_t)(m0 + r0s) * K + cBs;
  const size_t srcB = (size_t)(n0 + r0s) * K + cBs;
  const int d16 = tid * 16;

#define STAGE(slot, tt) do {                                      \
    char* bb = smem + (slot) * SLOT_BYTES;                        \
    gload_lds16(A8 + srcA + (size_t)(tt) * 64, bb + d16);         \
    gload_lds16(B8 + srcB + (size_t)(tt) * 64, bb + 8192 + d16);  \
  } while (0)

  // swizzled read bases: A row = wm*64+i*16+fr; B col = wn*32+j*16+fr; chunk hi
  const int slot16 = ((hi + 4 * (fr & 1)) ^ (fr >> 1)) << 4;
  const int aBase = (wm * 32 + (fr >> 1)) * 128 + slot16;          // + i*1024
  const int bBase = 8192 + (wn * 16 + (fr >> 1)) * 128 + slot16;   // + j*1024

  f32x4 master[4][2];
  i32x4 acc[4][2];
#pragma unroll
  for (int i = 0; i < 4; ++i)
#pragma unroll
    for (int j = 0; j < 2; ++j) {
      master[i][j] = (f32x4){0.f, 0.f, 0.f, 0.f};
      acc[i][j] = (i32x4){0, 0, 0, 0};
    }

  const int T = K / 64;  // 16
  __syncthreads();       // scales visible before any fold; no loads in flight yet
  STAGE(0, 0);
  STAGE(1, 1);
  STAGE(2, 2);

  for (int t = 0; t < T; ++t) {
    if (t < T - 2) { VMCNT(4); } else if (t == T - 2) { VMCNT(2); } else { VMCNT(0); }
    __builtin_amdgcn_s_barrier();
    if (t + 3 < T) STAGE((t + 3) & 3, t + 3);  // overwrites slot of t-1 (safe, see hdr)

    const char* ab = smem + (t & 3) * SLOT_BYTES;
    i32x4 a[4], b[2];
#pragma unroll
    for (int j = 0; j < 2; ++j) b[j] = *(const i32x4*)(ab + bBase + j * 1024);
#pragma unroll
    for (int i = 0; i < 4; ++i) a[i] = *(const i32x4*)(ab + aBase + i * 1024);

    __builtin_amdgcn_s_setprio(1);
#pragma unroll
    for (int i = 0; i < 4; ++i)
#pragma unroll
      for (int j = 0; j < 2; ++j)
        acc[i][j] = MFMAI8(a[i], b[j], acc[i][j]);
    __builtin_amdgcn_s_setprio(0);

    if ((t & 3) == 3) {  // exact i32 segment fold: master += sa*sb/4 * acc
      const int gI = t >> 2;
      f32x4 sav[4];
      float sbq[2];
#pragma unroll
      for (int i = 0; i < 4; ++i)
        sav[i] = *(const f32x4*)(sa_lds + gI * 128 + wm * 64 + i * 16 + hi * 4);
#pragma unroll
      for (int j = 0; j < 2; ++j)
        sbq[j] = sb_lds[gI * 128 + wn * 32 + j * 16 + fr] * 0.25f;
#pragma unroll
      for (int i = 0; i < 4; ++i)
#pragma unroll
        for (int j = 0; j < 2; ++j) {
#pragma unroll
          for (int r = 0; r < 4; ++r)
            master[i][j][r] += (float)acc[i][j][r] * sav[i][r] * sbq[j];
          acc[i][j] = (i32x4){0, 0, 0, 0};
        }
    }
  }
#undef STAGE

  // epilogue: C[row][col] = master + bias[col]
#pragma unroll
  for (int j = 0; j < 2; ++j) {
    const int col = n0 + wn * 32 + j * 16 + fr;
    const float bv = bias[col];
#pragma unroll
    for (int i = 0; i < 4; ++i) {
      const int row0 = m0 + wm * 64 + i * 16 + hi * 4;
#pragma unroll
      for (int r = 0; r < 4; ++r)
        C[(size_t)(row0 + r) * N + col] = master[i][j][r] + bv;
    }
  }
}

extern "C" void kernel_launch(void* const* d_in, const int* in_sizes, int n_in,
                              void* d_out, int out_size, void* d_ws, size_t ws_size,
                              hipStream_t stream) {
  const float* x = (const float*)d_in[0];     // [M,K]
  const float* w = (const float*)d_in[1];     // [N,K]
  const float* bias = (const float*)d_in[2];  // [N]
  float* out = (float*)d_out;

  const int MK = in_sizes[0];
  const int NK = in_sizes[1];
  const int N = in_sizes[2];
  const int K = NK / N;
  const int M = MK / K;

  signed char* qx8 = (signed char*)d_ws;           // [M,K] i8
  signed char* qw8 = qx8 + (size_t)MK;             // [N,K] i8
  float* sax = (float*)(qw8 + (size_t)NK);         // MK/256
  float* sbx = sax + (size_t)(MK / 256);           // NK/256

  const int gx = MK / 256;
  const int gtot = gx + NK / 256;
  qdq_i8<<<(gtot + 3) / 4, 256, 0, stream>>>(x, qx8, sax, gx, w, qw8, sbx, gtot);

  hipFuncSetAttribute((const void*)gemm_i8, hipFuncAttributeMaxDynamicSharedMemorySize,
                      LDS_TOTAL);
  dim3 grid((M / BM) * (N / BN));
  gemm_i8<<<grid, dim3(THREADS), LDS_TOTAL, stream>>>(qx8, qw8, sax, sbx, bias, out,
                                                      M, N, K);
}